// Round 17
// baseline (203.896 us; speedup 1.0000x reference)
//
#include <hip/hip_runtime.h>
#include <math.h>

// Problem constants: T=131072, D_IN=1024, NE=64, top_k=2
constexpr int T_TOKENS = 131072;
constexpr int D        = 1024;
constexpr float EPS_GAP = 1e-3f;   // flag threshold (bf16-split err ~1e-4 tail, 7.5-sigma miss margin)

typedef __attribute__((ext_vector_type(8))) short bf16x8;
typedef __attribute__((ext_vector_type(4))) float f32x4;
typedef __bf16 bf16v8 __attribute__((ext_vector_type(8)));
typedef float  f32v8  __attribute__((ext_vector_type(8)));

// split 8 fp32 into two bf16 planes (RNE): f ~= p0 + p1
__device__ __forceinline__ void split2(const float4 lo, const float4 hi,
                                       bf16x8& p0, bf16x8& p1) {
    f32v8 f = {lo.x, lo.y, lo.z, lo.w, hi.x, hi.y, hi.z, hi.w};
    bf16v8 h0 = __builtin_convertvector(f, bf16v8);
    f32v8 back = __builtin_convertvector(h0, f32v8);
    bf16v8 h1 = __builtin_convertvector(f - back, bf16v8);
    p0 = __builtin_bit_cast(bf16x8, h0);
    p1 = __builtin_bit_cast(bf16x8, h1);
}

// ---- Kernel 0: pre-split W into fragment-layout bf16 planes (256 KB) ------
// wpl[g*512 + (c*2+p)*64 + l] = plane_p( W[c*16 + (l&15)][g*32 + (l>>4)*8 .. +8] )
__global__ void prep_w(const float* __restrict__ W, bf16x8* __restrict__ wpl) {
    const int g = blockIdx.x;          // 0..31 (K window of 32)
    const int c = threadIdx.x >> 6;    // 0..3
    const int l = threadIdx.x & 63;
    const int e  = c * 16 + (l & 15);
    const int k0 = g * 32 + (l >> 4) * 8;
    const float4 lo = *(const float4*)(W + (long)e * D + k0);
    const float4 hi = *(const float4*)(W + (long)e * D + k0 + 4);
    bf16x8 p0, p1; split2(lo, hi, p0, p1);
    const int base = ((g * 4 + c) * 2) * 64 + l;
    wpl[base]      = p0;
    wpl[base + 64] = p1;
}

// ---- Kernel 1: zero-barrier MFMA router, 512B-run staging, 16-token waves --
// 2048 blocks x 256 thr (4 independent waves; NO __syncthreads).
// Wave = 16 tokens x 64 experts. A: 512B-contiguous-per-row chunks (KSTEP=128)
// staged via global_load_lds (2 rows per 1KB instruction) into wave-private
// double buffers; sync via counted s_waitcnt vmcnt(24) only.
// W: all 32 fragment loads issued at iteration top, BEFORE the stage issue,
// so in-order vmcnt retirement never drains the in-flight prefetch.
__global__ __launch_bounds__(256, 2)
void router_mfma(const float* __restrict__ x, const bf16x8* __restrict__ wpl,
                 float* __restrict__ out, unsigned* __restrict__ wcnt,
                 unsigned* __restrict__ wlist, unsigned cap)
{
    __shared__ __align__(16) char Xs[4][2][8192];   // [wave][buf][16 rows x 512B]

    const int tid = threadIdx.x;
    const int wv  = tid >> 6;
    const int l   = tid & 63;
    const int lg  = l >> 4;       // k-octet
    const int lr  = l & 15;       // token row in tile / expert in ctile
    const long t0 = (long)blockIdx.x * 64 + wv * 16;
    const int swz = (lr & 7) << 4;
    const int sil = (l & 31) * 16;   // staging: byte within 512B row window
    const char* xb = (const char*)x;

    f32x4 acc[4];
#pragma unroll
    for (int c = 0; c < 4; ++c) acc[c] = f32x4{0.f, 0.f, 0.f, 0.f};

#define STAGE(S, BUF)                                                          \
    {                                                                          \
        _Pragma("unroll")                                                      \
        for (int i = 0; i < 8; ++i) {                                          \
            const int rr = 2 * i + (l >> 5);                                   \
            const char* src = xb + (t0 + rr) * 4096L + (S) * 512               \
                              + (sil ^ ((rr & 7) << 4));                       \
            char* dst = &Xs[wv][BUF][i * 1024];                                \
            __builtin_amdgcn_global_load_lds(                                  \
                (const __attribute__((address_space(1))) void*)src,            \
                (__attribute__((address_space(3))) void*)dst, 16, 0, 0);       \
        }                                                                      \
    }

#define SUBSTEP(SUB)                                                           \
    {                                                                          \
        const int c0 = (SUB) * 128 + lg * 32;                                  \
        const float4 lo = *(const float4*)(wb + lr * 512 + (c0 ^ swz));        \
        const float4 hi = *(const float4*)(wb + lr * 512 + ((c0 + 16) ^ swz)); \
        bf16x8 a0, a1;                                                         \
        split2(lo, hi, a0, a1);                                                \
        _Pragma("unroll")                                                      \
        for (int c = 0; c < 4; ++c) {                                          \
            acc[c] = __builtin_amdgcn_mfma_f32_16x16x32_bf16(a0, w[SUB][c*2+0], acc[c], 0, 0, 0); \
            acc[c] = __builtin_amdgcn_mfma_f32_16x16x32_bf16(a1, w[SUB][c*2+0], acc[c], 0, 0, 0); \
            acc[c] = __builtin_amdgcn_mfma_f32_16x16x32_bf16(a0, w[SUB][c*2+1], acc[c], 0, 0, 0); \
        }                                                                      \
    }

    STAGE(0, 0);

#pragma unroll 1
    for (int s = 0; s < 8; ++s) {
        const int buf = s & 1;
        // 1. W fragments for this chunk's 4 k-windows (L1/L2-hot), all first
        bf16x8 w[4][8];
#pragma unroll
        for (int g = 0; g < 4; ++g)
#pragma unroll
            for (int q = 0; q < 8; ++q)
                w[g][q] = wpl[(size_t)(s * 4 + g) * 512 + q * 64 + l];
        // 2. issue next chunk's staging
        if (s + 1 < 8) { if (buf) STAGE(s + 1, 0) else STAGE(s + 1, 1) }
        // 3. counted wait: retires stage(s) (+ oldest W half); keeps
        //    stage(s+1) (8) + newest W (16) = 24 in flight
        asm volatile("s_waitcnt vmcnt(24)" ::: "memory");
        __builtin_amdgcn_sched_barrier(0);
        // 4. compute chunk s (4 substeps of 32 k)
        const char* wb = &Xs[wv][buf][0];
        SUBSTEP(0)
        SUBSTEP(1)
        SUBSTEP(2)
        SUBSTEP(3)
    }
#undef SUBSTEP
#undef STAGE

    // ---- epilogue: top-3 per token, provisional write + gap-flag ----
    // C/D: col = lane&15 (expert in ctile), row = (lane>>4)*4 + reg (token)
#pragma unroll
    for (int r = 0; r < 4; ++r) {
        float v1 = acc[0][r]; int i1 = lr;
        float v2 = -INFINITY;  int i2 = 1 << 20;
        float v3 = -INFINITY;
#pragma unroll
        for (int c = 1; c < 4; ++c) {
            const float v = acc[c][r]; const int e = lr + 16 * c;
            if (v > v1)      { v3 = v2; v2 = v1; i2 = i1; v1 = v; i1 = e; }
            else if (v > v2) { v3 = v2; v2 = v;  i2 = e; }
            else if (v > v3) { v3 = v; }
        }
#pragma unroll
        for (int m = 8; m >= 1; m >>= 1) {
            const float ov1 = __shfl_xor(v1, m);
            const int   oi1 = __shfl_xor(i1, m);
            const float ov2 = __shfl_xor(v2, m);
            const int   oi2 = __shfl_xor(i2, m);
            const float ov3 = __shfl_xor(v3, m);
            const bool tv = v1 >= ov1;
            const float x2 = tv ? v2 : ov2, x3 = tv ? v3 : ov3;
            const float y1 = tv ? ov1 : v1, y2 = tv ? ov2 : v2;
            const float nv3 = (x2 >= y1) ? fmaxf(x3, y1) : fmaxf(x2, y2);
            const bool aw = (ov1 > v1) || (ov1 == v1 && oi1 < i1);
            const float nv1 = aw ? ov1 : v1; const int ni1 = aw ? oi1 : i1;
            const float c1v = aw ? v1  : ov1; const int c1i = aw ? i1  : oi1;
            const float c2v = aw ? ov2 : v2;  const int c2i = aw ? oi2 : i2;
            const bool bw = (c1v > c2v) || (c1v == c2v && c1i < c2i);
            v1 = nv1; i1 = ni1;
            v2 = bw ? c1v : c2v; i2 = bw ? c1i : c2i;
            v3 = nv3;
        }
        if (lr == 0) {
            const long t = t0 + lg * 4 + r;
            const float e  = expf(v2 - v1);
            const float dn = 1.0f + e;
            out[t * 2 + 0] = (float)i1;
            out[t * 2 + 1] = (float)i2;
            out[(long)T_TOKENS * 2 + t * 2 + 0] = 1.0f / dn;
            out[(long)T_TOKENS * 2 + t * 2 + 1] = e / dn;
            if (v1 - v2 < EPS_GAP || v2 - v3 < EPS_GAP) {
                const unsigned p = atomicAdd(wcnt, 1u);
                if (p < cap) wlist[p] = (unsigned)t;
            }
        }
    }
}

// ---- Kernel 2: exact-chain fixup, 4 waves/token (one per OpenBLAS panel) --
// Exact OpenBLAS-SKYLAKEX chain (verified R7+): panels 320/320/192/192,
// ascending-k fp32 FMA chain per panel, sequential rounded folds.
__global__ __launch_bounds__(256)
void router_fixup(const float* __restrict__ x, const float* __restrict__ W,
                  float* __restrict__ out, const unsigned* __restrict__ wcnt,
                  const unsigned* __restrict__ wlist, unsigned cap)
{
    __shared__ float ps[4][64];
    unsigned cnt = wcnt[0]; if (cnt > cap) cnt = cap;
    const int wv = threadIdx.x >> 6;   // panel id
    const int l  = threadIdx.x & 63;   // expert
    const int kb = (wv == 0) ? 0 : (wv == 1) ? 320 : (wv == 2) ? 640 : 832;
    const int ke = (wv == 0) ? 320 : (wv == 1) ? 640 : (wv == 2) ? 832 : 1024;

    for (unsigned it = blockIdx.x; it < cnt; it += gridDim.x) {
        const long t = (long)wlist[it];
        const float* xr = x + t * (long)D;
        const float* wr = W + (long)l * D;
        float accP = 0.f;
#pragma unroll 4
        for (int k = kb; k < ke; k += 4) {
            const float4 xv = *(const float4*)(xr + k);
            const float4 wvv = *(const float4*)(wr + k);
            accP = fmaf(xv.x, wvv.x, accP);
            accP = fmaf(xv.y, wvv.y, accP);
            accP = fmaf(xv.z, wvv.z, accP);
            accP = fmaf(xv.w, wvv.w, accP);
        }
        ps[wv][l] = accP;
        __syncthreads();
        if (wv == 0) {
            const float accT = __fadd_rn(__fadd_rn(__fadd_rn(ps[0][l], ps[1][l]), ps[2][l]), ps[3][l]);
            float v1 = accT; int i1 = l;
            float v2 = -INFINITY; int i2 = 1 << 20;
#pragma unroll
            for (int m = 32; m >= 1; m >>= 1) {
                const float ov1 = __shfl_xor(v1, m);
                const int   oi1 = __shfl_xor(i1, m);
                const float ov2 = __shfl_xor(v2, m);
                const int   oi2 = __shfl_xor(i2, m);
                const bool aw = (ov1 > v1) || (ov1 == v1 && oi1 < i1);
                const float nv1 = aw ? ov1 : v1; const int ni1 = aw ? oi1 : i1;
                const float c1v = aw ? v1  : ov1; const int c1i = aw ? i1  : oi1;
                const float c2v = aw ? ov2 : v2;  const int c2i = aw ? oi2 : i2;
                const bool bw = (c1v > c2v) || (c1v == c2v && c1i < c2i);
                v1 = nv1; i1 = ni1;
                v2 = bw ? c1v : c2v; i2 = bw ? c1i : c2i;
            }
            if (l == 0) {
                const float e  = expf(v2 - v1);
                const float dn = 1.0f + e;
                out[t * 2 + 0] = (float)i1;
                out[t * 2 + 1] = (float)i2;
                out[(long)T_TOKENS * 2 + t * 2 + 0] = 1.0f / dn;
                out[(long)T_TOKENS * 2 + t * 2 + 1] = e / dn;
            }
        }
        __syncthreads();
    }
}

extern "C" void kernel_launch(void* const* d_in, const int* in_sizes, int n_in,
                              void* d_out, int out_size, void* d_ws, size_t ws_size,
                              hipStream_t stream) {
    const float* x = (const float*)d_in[0];
    const float* W = (const float*)d_in[1];
    float* out = (float*)d_out;

    // workspace layout: [0,64) wcnt | [1024, 1024+256K) W frag planes | wlist
    unsigned* wcnt  = (unsigned*)d_ws;
    bf16x8*   wpl   = (bf16x8*)((char*)d_ws + 1024);
    unsigned* wlist = (unsigned*)((char*)d_ws + 1024 + 262144);
    size_t rem = (ws_size - 1024 - 262144) / 4;
    unsigned cap = (unsigned)(rem > (1u << 22) ? (1u << 22) : rem);

    (void)hipMemsetAsync(d_ws, 0, 64, stream);
    prep_w<<<dim3(32), dim3(256), 0, stream>>>(W, wpl);
    router_mfma<<<dim3(T_TOKENS / 64), dim3(256), 0, stream>>>(x, wpl, out, wcnt, wlist, cap);
    router_fixup<<<dim3(512), dim3(256), 0, stream>>>(x, W, out, wcnt, wlist, cap);
}